// Round 9
// baseline (224.649 us; speedup 1.0000x reference)
//
#include <hip/hip_runtime.h>
#include <hip/hip_bf16.h>
#include <cstdint>
#include <cstddef>

typedef __bf16 bf16_t;
typedef __bf16 bf16x4 __attribute__((ext_vector_type(4)));
typedef __bf16 bf16x8 __attribute__((ext_vector_type(8)));
typedef float  f32x4  __attribute__((ext_vector_type(4)));

enum { EP_QKV = 0 };

// async global->LDS, 16B per lane; LDS dest = wave-uniform base + lane*16
__device__ __forceinline__ void async_copy16(const void* g, void* l) {
  __builtin_amdgcn_global_load_lds(
      (const __attribute__((address_space(1))) void*)g,
      (__attribute__((address_space(3))) void*)l, 16, 0, 0);
}

// ---------------- conversions ----------------

__global__ void f32_to_bf16_kernel(const float* __restrict__ in, bf16_t* __restrict__ out) {
  size_t i = ((size_t)blockIdx.x * blockDim.x + threadIdx.x) * 8;
  float4 a = *(const float4*)(in + i);
  float4 b = *(const float4*)(in + i + 4);
  bf16x8 o;
  o[0] = (__bf16)a.x; o[1] = (__bf16)a.y; o[2] = (__bf16)a.z; o[3] = (__bf16)a.w;
  o[4] = (__bf16)b.x; o[5] = (__bf16)b.y; o[6] = (__bf16)b.z; o[7] = (__bf16)b.w;
  *(bf16x8*)(out + i) = o;
}

// 4x fused: in [1024][1024] f32 -> out [1024][1024]^T bf16, selected by blockIdx.z
__global__ void transpose4_kernel(const float* __restrict__ w0, const float* __restrict__ w1,
                                  const float* __restrict__ w2, const float* __restrict__ w3,
                                  bf16_t* __restrict__ o0, bf16_t* __restrict__ o1,
                                  bf16_t* __restrict__ o2, bf16_t* __restrict__ o3) {
  int z = blockIdx.z;
  const float* in = (z == 0) ? w0 : (z == 1) ? w1 : (z == 2) ? w2 : w3;
  bf16_t* out = (z == 0) ? o0 : (z == 1) ? o1 : (z == 2) ? o2 : o3;
  __shared__ float tile[32][33];
  int x = threadIdx.x, y = threadIdx.y;
  int c0 = blockIdx.x * 32, r0 = blockIdx.y * 32;
  #pragma unroll
  for (int i = 0; i < 32; i += 8) tile[y + i][x] = in[(size_t)(r0 + y + i) * 1024 + c0 + x];
  __syncthreads();
  #pragma unroll
  for (int i = 0; i < 32; i += 8)
    out[(size_t)(c0 + y + i) * 1024 + r0 + x] = (__bf16)tile[x][y + i];
}

// in [rows][cols] f32 -> out [cols][rows] bf16 ; rows, cols multiples of 32
__global__ void transpose_f32_bf16_kernel(const float* __restrict__ in, bf16_t* __restrict__ out,
                                          int rows, int cols) {
  __shared__ float tile[32][33];
  int x = threadIdx.x, y = threadIdx.y;
  int c0 = blockIdx.x * 32, r0 = blockIdx.y * 32;
  #pragma unroll
  for (int i = 0; i < 32; i += 8) tile[y + i][x] = in[(size_t)(r0 + y + i) * cols + c0 + x];
  __syncthreads();
  #pragma unroll
  for (int i = 0; i < 32; i += 8)
    out[(size_t)(c0 + y + i) * rows + r0 + x] = (__bf16)tile[x][y + i];
}

// ---------------- LRPE cos/sin table via rotation recurrence ----------------

__global__ __launch_bounds__(256) void lrpe_table2_kernel(const float* __restrict__ theta,
                                                          float2* __restrict__ tab) {
  int col = blockIdx.x * 256 + threadIdx.x;
  int n0 = blockIdx.y * 32;
  float th = theta[col];
  float c0, s0, dc, ds;
  sincosf(th * (float)n0, &s0, &c0);
  sincosf(th, &ds, &dc);
  float2* p = tab + (size_t)n0 * 1024 + col;
  #pragma unroll
  for (int i = 0; i < 32; ++i) {
    *p = make_float2(c0, s0);
    float c1 = c0 * dc - s0 * ds;
    float s1 = s0 * dc + c0 * ds;
    c0 = c1; s0 = s1;
    p += 1024;
  }
}

// ---------------- GEMM (R3-proven form, widened tile): 128x256, 4 waves, 48KB buffer ----------------
// Template + RUNTIME K + #pragma unroll 1 (rolled K-loop, I$-friendly — R8-verified).
// 2x2 waves, each owns 64x128 of C: 64 MFMA + 24 ds_read per K-step per wave
// (2x the MFMA:staging ratio of 128^2 — attacks the 29%-VALUBusy staging overhead).
// XOR-swizzled LDS via pre-swizzled global source. Grid 384 = 2 blocks/CU.

template <int MODE, int BM, int BN, int GX, int WAVES_M, int WAVES_N>
__global__ __launch_bounds__(WAVES_M * WAVES_N * 64) void gemm2(
    const bf16_t* __restrict__ A, const bf16_t* __restrict__ Bt,
    const float2* __restrict__ lrpe, const bf16_t* __restrict__ gate,
    bf16_t* __restrict__ qrb, bf16_t* __restrict__ krb, bf16_t* __restrict__ vbb,
    float* __restrict__ fout, bf16_t* __restrict__ bout, int K) {
  constexpr int BK = 64;
  constexpr int WAVES = WAVES_M * WAVES_N;
  constexpr int T = WAVES * 64;
  constexpr int WM = BM / WAVES_M, WN = BN / WAVES_N;
  constexpr int MT = WM / 16, NT = WN / 16;
  __shared__ alignas(16) bf16_t lA[BM * BK];
  __shared__ alignas(16) bf16_t lB[BN * BK];
  const int tid = threadIdx.x, w = tid >> 6, l = tid & 63;
  const int wm = w / WAVES_N, wn = w % WAVES_N;
  const int l15 = l & 15, lg = l >> 4;
  const int cpx = gridDim.x >> 3;
  const int id = blockIdx.x;
  const int sw = (id & 7) * cpx + (id >> 3);   // XCD-contiguous, bijective (grid%8==0)
  const int by = sw / GX, bx = sw % GX;
  const int r0 = by * BM, c0 = bx * BN;
  const int srow_l = l >> 3, sslot = l & 7;
  f32x4 acc[MT][NT] = {};
  #pragma unroll 1
  for (int k0 = 0; k0 < K; k0 += BK) {
    #pragma unroll
    for (int i = 0; i < BM * 8 / T; ++i) {
      int seg = i * WAVES + w;
      int row = seg * 8 + srow_l;
      int xs = sslot ^ (row & 7);
      async_copy16(A + (size_t)(r0 + row) * K + k0 + xs * 8, lA + seg * 512);
    }
    #pragma unroll
    for (int i = 0; i < BN * 8 / T; ++i) {
      int seg = i * WAVES + w;
      int row = seg * 8 + srow_l;
      int xs = sslot ^ (row & 7);
      async_copy16(Bt + (size_t)(c0 + row) * K + k0 + xs * 8, lB + seg * 512);
    }
    __syncthreads();
    #pragma unroll
    for (int ks = 0; ks < BK / 32; ++ks) {
      bf16x8 af[MT], bfr[NT];
      #pragma unroll
      for (int mt = 0; mt < MT; ++mt) {
        int row = wm * WM + mt * 16 + l15;
        int s = (ks * 4 + lg) ^ (row & 7);
        af[mt] = *(const bf16x8*)(lA + row * BK + s * 8);
      }
      #pragma unroll
      for (int nt = 0; nt < NT; ++nt) {
        int row = wn * WN + nt * 16 + l15;
        int s = (ks * 4 + lg) ^ (row & 7);
        bfr[nt] = *(const bf16x8*)(lB + row * BK + s * 8);
      }
      #pragma unroll
      for (int mt = 0; mt < MT; ++mt)
        #pragma unroll
        for (int nt = 0; nt < NT; ++nt)
          acc[mt][nt] = __builtin_amdgcn_mfma_f32_16x16x32_bf16(af[mt], bfr[nt], acc[mt][nt], 0, 0, 0);
    }
    __syncthreads();
  }
  #pragma unroll
  for (int mt = 0; mt < MT; ++mt)
  #pragma unroll
  for (int nt = 0; nt < NT; ++nt)
  #pragma unroll
  for (int r = 0; r < 4; ++r) {
    int grow = r0 + wm * WM + mt * 16 + lg * 4 + r;
    int gcol = c0 + wn * WN + nt * 16 + l15;
    float v = acc[mt][nt][r];
    if constexpr (MODE == EP_QKV) {
      int sect = gcol >> 10, col = gcol & 1023;   // block-uniform sect
      int b = grow >> 11, n = grow & 2047;
      int h = col >> 6, d = col & 63;
      if (sect == 2) {
        vbb[((size_t)(b * 16 + h) * 2048 + n) * 64 + d] = (__bf16)v;
      } else {
        float sv = v / (1.f + expf(-v));      // silu
        float2 cs = lrpe[(size_t)n * 1024 + col];
        bf16_t* dst = sect ? krb : qrb;
        size_t base = ((size_t)(b * 16 + h) * 2048 + n) * 128 + d;
        dst[base] = (__bf16)(sv * cs.x);
        dst[base + 64] = (__bf16)(sv * cs.y);
      }
    }
  }
}

// ---------------- WO GEMM with fused gate: owo = (attno @ Wo) * sigmoid(xg1b @ G2) ----------------
// 64x128 tile; RUNTIME K + unroll 1 keeps the loop rolled.

__global__ __launch_bounds__(256) void gemm_wo(
    const bf16_t* __restrict__ A, const bf16_t* __restrict__ Bt,
    const bf16_t* __restrict__ xg1b, const bf16_t* __restrict__ G2T,
    float* __restrict__ fout, int K) {
  constexpr int BK = 64, GX = 8;
  __shared__ alignas(16) bf16_t lA[64 * BK];
  __shared__ alignas(16) bf16_t lB[128 * BK];
  const int tid = threadIdx.x, w = tid >> 6, l = tid & 63;
  const int wm = w >> 1, wn = w & 1;
  const int l15 = l & 15, lg = l >> 4;
  const int cpx = gridDim.x >> 3;
  const int id = blockIdx.x;
  const int sw = (id & 7) * cpx + (id >> 3);
  const int by = sw / GX, bx = sw % GX;
  const int r0 = by * 64, c0 = bx * 128;
  const int srow_l = l >> 3, sslot = l & 7;
  f32x4 acc[2][4] = {};
  #pragma unroll 1
  for (int k0 = 0; k0 < K; k0 += BK) {
    #pragma unroll
    for (int i = 0; i < 2; ++i) {
      int seg = i * 4 + w, row = seg * 8 + srow_l, xs = sslot ^ (row & 7);
      async_copy16(A + (size_t)(r0 + row) * K + k0 + xs * 8, lA + seg * 512);
    }
    #pragma unroll
    for (int i = 0; i < 4; ++i) {
      int seg = i * 4 + w, row = seg * 8 + srow_l, xs = sslot ^ (row & 7);
      async_copy16(Bt + (size_t)(c0 + row) * K + k0 + xs * 8, lB + seg * 512);
    }
    __syncthreads();
    #pragma unroll
    for (int ks = 0; ks < 2; ++ks) {
      bf16x8 af[2], bfr[4];
      #pragma unroll
      for (int mt = 0; mt < 2; ++mt) {
        int row = wm * 32 + mt * 16 + l15;
        int s = (ks * 4 + lg) ^ (row & 7);
        af[mt] = *(const bf16x8*)(lA + row * BK + s * 8);
      }
      #pragma unroll
      for (int nt = 0; nt < 4; ++nt) {
        int row = wn * 64 + nt * 16 + l15;
        int s = (ks * 4 + lg) ^ (row & 7);
        bfr[nt] = *(const bf16x8*)(lB + row * BK + s * 8);
      }
      #pragma unroll
      for (int mt = 0; mt < 2; ++mt)
        #pragma unroll
        for (int nt = 0; nt < 4; ++nt)
          acc[mt][nt] = __builtin_amdgcn_mfma_f32_16x16x32_bf16(af[mt], bfr[nt], acc[mt][nt], 0, 0, 0);
    }
    __syncthreads();
  }
  // ---- fused gate K-step ----
  #pragma unroll
  for (int i = 0; i < 2; ++i) {
    int seg = i * 4 + w, row = seg * 8 + srow_l, xs = sslot ^ (row & 7);
    async_copy16(xg1b + (size_t)(r0 + row) * 64 + xs * 8, lA + seg * 512);
  }
  #pragma unroll
  for (int i = 0; i < 4; ++i) {
    int seg = i * 4 + w, row = seg * 8 + srow_l, xs = sslot ^ (row & 7);
    async_copy16(G2T + (size_t)(c0 + row) * 64 + xs * 8, lB + seg * 512);
  }
  __syncthreads();
  f32x4 acc2[2][4] = {};
  #pragma unroll
  for (int ks = 0; ks < 2; ++ks) {
    bf16x8 af[2], bfr[4];
    #pragma unroll
    for (int mt = 0; mt < 2; ++mt) {
      int row = wm * 32 + mt * 16 + l15;
      int s = (ks * 4 + lg) ^ (row & 7);
      af[mt] = *(const bf16x8*)(lA + row * BK + s * 8);
    }
    #pragma unroll
    for (int nt = 0; nt < 4; ++nt) {
      int row = wn * 64 + nt * 16 + l15;
      int s = (ks * 4 + lg) ^ (row & 7);
      bfr[nt] = *(const bf16x8*)(lB + row * BK + s * 8);
    }
    #pragma unroll
    for (int mt = 0; mt < 2; ++mt)
      #pragma unroll
      for (int nt = 0; nt < 4; ++nt)
        acc2[mt][nt] = __builtin_amdgcn_mfma_f32_16x16x32_bf16(af[mt], bfr[nt], acc2[mt][nt], 0, 0, 0);
  }
  #pragma unroll
  for (int mt = 0; mt < 2; ++mt)
  #pragma unroll
  for (int nt = 0; nt < 4; ++nt)
  #pragma unroll
  for (int r = 0; r < 4; ++r) {
    int grow = r0 + wm * 32 + mt * 16 + lg * 4 + r;
    int gcol = c0 + wn * 64 + nt * 16 + l15;
    float g = 1.f / (1.f + expf(-acc2[mt][nt][r]));
    fout[(size_t)grow * 1024 + gcol] = acc[mt][nt][r] * g;
  }
}

// ---------------- xg1b = bf16(x @ G1)  ([4096][64]) ----------------

__global__ __launch_bounds__(512) void xg1_kernel(const float* __restrict__ x,
                                                  const float* __restrict__ G1,
                                                  bf16_t* __restrict__ xg1b) {
  int r0 = blockIdx.x * 8, t = threadIdx.x;
  __shared__ float xs[8][1024];
  __shared__ float part[8][8][64];
  const float* xr = x + (size_t)r0 * 1024;
  #pragma unroll
  for (int i = 0; i < 4; ++i)
    ((float4*)&xs[0][0])[t + i * 512] = ((const float4*)xr)[t + i * 512];
  __syncthreads();
  int cc = t & 63, kh = t >> 6;
  float acc[8] = {0, 0, 0, 0, 0, 0, 0, 0};
  for (int k = kh * 128; k < kh * 128 + 128; ++k) {
    float g = G1[(size_t)k * 64 + cc];
    #pragma unroll
    for (int rr = 0; rr < 8; ++rr) acc[rr] += xs[rr][k] * g;
  }
  #pragma unroll
  for (int rr = 0; rr < 8; ++rr) part[kh][rr][cc] = acc[rr];
  __syncthreads();
  int r2 = t >> 6, c2 = t & 63;
  float s2 = 0.f;
  #pragma unroll
  for (int j = 0; j < 8; ++j) s2 += part[j][r2][c2];
  xg1b[(size_t)(r0 + r2) * 64 + c2] = (__bf16)s2;
}

// ---------------- chunk states: cstate[bh][c][dv][dk] = sum_m v[m][dv]*k[m][dk] ----------------

__global__ __launch_bounds__(256) void chunk_state_kernel(const bf16_t* __restrict__ kr,
                                                          const bf16_t* __restrict__ vb,
                                                          float* __restrict__ cstate) {
  const int c = blockIdx.x, bh = blockIdx.y;
  const int tid = threadIdx.x, w = tid >> 6, l = tid & 63;
  const int l15 = l & 15, lg = l >> 4;
  __shared__ alignas(16) bf16_t kT[128][144];
  __shared__ alignas(16) bf16_t vT[64][144];
  const bf16_t* kb = kr + ((size_t)bh * 2048 + c * 128) * 128;
  const bf16_t* vsrc = vb + ((size_t)bh * 2048 + c * 128) * 64;
  {
    int m = tid >> 1, half = tid & 1;
    #pragma unroll
    for (int i = 0; i < 8; ++i) {
      bf16x8 kv = *(const bf16x8*)(kb + (size_t)m * 128 + half * 64 + i * 8);
      #pragma unroll
      for (int j = 0; j < 8; ++j) kT[half * 64 + i * 8 + j][m] = kv[j];
    }
    int dv0 = half * 32;
    #pragma unroll
    for (int i = 0; i < 4; ++i) {
      bf16x8 vv = *(const bf16x8*)(vsrc + (size_t)m * 64 + dv0 + i * 8);
      #pragma unroll
      for (int j = 0; j < 8; ++j) vT[dv0 + i * 8 + j][m] = vv[j];
    }
  }
  __syncthreads();
  f32x4 acc[4][2] = {};
  #pragma unroll
  for (int km = 0; km < 4; ++km) {
    bf16x8 a[4], b2[2];
    #pragma unroll
    for (int mt = 0; mt < 4; ++mt) a[mt] = *(const bf16x8*)&vT[mt * 16 + l15][km * 32 + lg * 8];
    #pragma unroll
    for (int nt = 0; nt < 2; ++nt) b2[nt] = *(const bf16x8*)&kT[w * 32 + nt * 16 + l15][km * 32 + lg * 8];
    #pragma unroll
    for (int mt = 0; mt < 4; ++mt)
      #pragma unroll
      for (int nt = 0; nt < 2; ++nt)
        acc[mt][nt] = __builtin_amdgcn_mfma_f32_16x16x32_bf16(a[mt], b2[nt], acc[mt][nt], 0, 0, 0);
  }
  float* out = cstate + ((size_t)bh * 16 + c) * 8192;
  #pragma unroll
  for (int mt = 0; mt < 4; ++mt)
  #pragma unroll
  for (int nt = 0; nt < 2; ++nt)
  #pragma unroll
  for (int r = 0; r < 4; ++r) {
    int dv = mt * 16 + lg * 4 + r;
    int dk = w * 32 + nt * 16 + l15;
    out[dv * 128 + dk] = acc[mt][nt][r];
  }
}

// ---------------- exclusive prefix over chunks (256 blocks: 8 e-slices x 32 bh) ----------------

__global__ __launch_bounds__(256) void prefix_state_kernel(const float* __restrict__ cstate,
                                                           bf16_t* __restrict__ pstate) {
  int bh = blockIdx.y;
  int e0 = blockIdx.x * 1024 + threadIdx.x * 4;
  const float* cs = cstate + (size_t)bh * 16 * 8192 + e0;
  bf16_t* ps = pstate + (size_t)bh * 16 * 8192 + e0;
  float ax = 0.f, ay = 0.f, az = 0.f, aw = 0.f;
  #pragma unroll
  for (int c = 0; c < 16; ++c) {
    bf16x4 o;
    o[0] = (__bf16)ax; o[1] = (__bf16)ay; o[2] = (__bf16)az; o[3] = (__bf16)aw;
    *(bf16x4*)(ps + (size_t)c * 8192) = o;
    float4 v = *(const float4*)(cs + (size_t)c * 8192);
    ax += v.x; ay += v.y; az += v.z; aw += v.w;
  }
}

// ---------------- attention per (b,h,chunk): out = q@S + (q@k^T ∘ tril)@v ----------------

__global__ __launch_bounds__(256) void attn_kernel(const bf16_t* __restrict__ qr,
                                                   const bf16_t* __restrict__ kr,
                                                   const bf16_t* __restrict__ vb,
                                                   const bf16_t* __restrict__ pstate,
                                                   bf16_t* __restrict__ attno) {
  const int c = blockIdx.x, bh = blockIdx.y;
  const int b = bh >> 4, h = bh & 15;
  const int tid = threadIdx.x, w = tid >> 6, l = tid & 63;
  const int wr = w >> 1, wc = w & 1, l15 = l & 15, lg = l >> 4;
  __shared__ alignas(16) bf16_t e_lds[128][144];
  __shared__ alignas(16) bf16_t vT[64][144];
  const int n0 = c * 128;
  const bf16_t* qb = qr + (size_t)bh * 2048 * 128;
  const bf16_t* kb = kr + (size_t)bh * 2048 * 128;
  const bf16_t* vsrc = vb + ((size_t)bh * 2048 + n0) * 64;
  const bf16_t* sb = pstate + ((size_t)bh * 16 + c) * 8192;
  {  // stage v^T
    int m = tid >> 1, dv0 = (tid & 1) * 32;
    #pragma unroll
    for (int i = 0; i < 4; ++i) {
      bf16x8 vv = *(const bf16x8*)(vsrc + (size_t)m * 64 + dv0 + i * 8);
      #pragma unroll
      for (int j = 0; j < 8; ++j) vT[dv0 + i * 8 + j][m] = vv[j];
    }
  }
  f32x4 acc_e[4][4] = {};
  f32x4 acc[4][2] = {};
  #pragma unroll
  for (int kk = 0; kk < 4; ++kk) {  // K over dk=128
    bf16x8 af[4], bk[4], bs[2];
    #pragma unroll
    for (int mt = 0; mt < 4; ++mt)
      af[mt] = *(const bf16x8*)(qb + (size_t)(n0 + wr * 64 + mt * 16 + l15) * 128 + kk * 32 + lg * 8);
    #pragma unroll
    for (int nt = 0; nt < 4; ++nt)
      bk[nt] = *(const bf16x8*)(kb + (size_t)(n0 + wc * 64 + nt * 16 + l15) * 128 + kk * 32 + lg * 8);
    #pragma unroll
    for (int nt = 0; nt < 2; ++nt)
      bs[nt] = *(const bf16x8*)(sb + (size_t)(wc * 32 + nt * 16 + l15) * 128 + kk * 32 + lg * 8);
    #pragma unroll
    for (int mt = 0; mt < 4; ++mt) {
      #pragma unroll
      for (int nt = 0; nt < 4; ++nt)
        acc_e[mt][nt] = __builtin_amdgcn_mfma_f32_16x16x32_bf16(af[mt], bk[nt], acc_e[mt][nt], 0, 0, 0);
      #pragma unroll
      for (int nt = 0; nt < 2; ++nt)
        acc[mt][nt] = __builtin_amdgcn_mfma_f32_16x16x32_bf16(af[mt], bs[nt], acc[mt][nt], 0, 0, 0);
    }
  }
  #pragma unroll
  for (int mt = 0; mt < 4; ++mt)
  #pragma unroll
  for (int nt = 0; nt < 4; ++nt)
  #pragma unroll
  for (int r = 0; r < 4; ++r) {
    int row = wr * 64 + mt * 16 + lg * 4 + r;   // n (query)
    int col = wc * 64 + nt * 16 + l15;          // m (key)
    float v = (col <= row) ? acc_e[mt][nt][r] : 0.f;
    e_lds[row][col] = (__bf16)v;
  }
  __syncthreads();
  #pragma unroll
  for (int km = 0; km < 4; ++km) {  // K over m=128
    bf16x8 af[4], bv[2];
    #pragma unroll
    for (int mt = 0; mt < 4; ++mt)
      af[mt] = *(const bf16x8*)&e_lds[wr * 64 + mt * 16 + l15][km * 32 + lg * 8];
    #pragma unroll
    for (int nt = 0; nt < 2; ++nt)
      bv[nt] = *(const bf16x8*)&vT[wc * 32 + nt * 16 + l15][km * 32 + lg * 8];
    #pragma unroll
    for (int mt = 0; mt < 4; ++mt)
      #pragma unroll
      for (int nt = 0; nt < 2; ++nt)
        acc[mt][nt] = __builtin_amdgcn_mfma_f32_16x16x32_bf16(af[mt], bv[nt], acc[mt][nt], 0, 0, 0);
  }
  #pragma unroll
  for (int mt = 0; mt < 4; ++mt)
  #pragma unroll
  for (int nt = 0; nt < 2; ++nt)
  #pragma unroll
  for (int r = 0; r < 4; ++r) {
    int row = n0 + wr * 64 + mt * 16 + lg * 4 + r;
    int dv = wc * 32 + nt * 16 + l15;
    attno[((size_t)b * 2048 + row) * 1024 + h * 64 + dv] = (__bf16)acc[mt][nt][r];
  }
}

// ---------------- LayerNorm ----------------

__global__ __launch_bounds__(256) void ln_kernel(const float* __restrict__ owo,
                                                 const float* __restrict__ gamma,
                                                 const float* __restrict__ beta,
                                                 float* __restrict__ out) {
  int r = blockIdx.x, t = threadIdx.x;
  const float4 o = ((const float4*)(owo + (size_t)r * 1024))[t];
  float sum = o.x + o.y + o.z + o.w;
  float ss = o.x * o.x + o.y * o.y + o.z * o.z + o.w * o.w;
  #pragma unroll
  for (int off = 32; off > 0; off >>= 1) {
    sum += __shfl_down(sum, off);
    ss += __shfl_down(ss, off);
  }
  __shared__ float rs[4], rq[4];
  if ((t & 63) == 0) { rs[t >> 6] = sum; rq[t >> 6] = ss; }
  __syncthreads();
  sum = rs[0] + rs[1] + rs[2] + rs[3];
  ss = rq[0] + rq[1] + rq[2] + rq[3];
  float mean = sum * (1.f / 1024.f);
  float var = ss * (1.f / 1024.f) - mean * mean;
  float inv = rsqrtf(var + 1e-5f);
  const float4 g = ((const float4*)gamma)[t];
  const float4 be = ((const float4*)beta)[t];
  float4 res;
  res.x = (o.x - mean) * inv * g.x + be.x;
  res.y = (o.y - mean) * inv * g.y + be.y;
  res.z = (o.z - mean) * inv * g.z + be.z;
  res.w = (o.w - mean) * inv * g.w + be.w;
  ((float4*)(out + (size_t)r * 1024))[t] = res;
}

// ---------------- launch ----------------

extern "C" void kernel_launch(void* const* d_in, const int* in_sizes, int n_in,
                              void* d_out, int out_size, void* d_ws, size_t ws_size,
                              hipStream_t stream) {
  const float* x = (const float*)d_in[0];
  const float* Wq = (const float*)d_in[1];
  const float* Wk = (const float*)d_in[2];
  const float* Wv = (const float*)d_in[3];
  const float* Wo = (const float*)d_in[4];
  const float* G1 = (const float*)d_in[5];
  const float* G2 = (const float*)d_in[6];
  const float* gamma = (const float*)d_in[7];
  const float* beta = (const float*)d_in[8];
  const float* theta = (const float*)d_in[9];

  char* w8 = (char*)d_ws;
  size_t off = 0;
  auto take = [&](size_t n) { char* p = w8 + off; off += (n + 255) & ~(size_t)255; return (void*)p; };

  bf16_t* xb    = (bf16_t*)take((size_t)4096 * 1024 * 2);   // reused as attno
  bf16_t* qkvT  = (bf16_t*)take((size_t)3072 * 1024 * 2);   // [WqT|WkT|WvT]
  bf16_t* WoT   = (bf16_t*)take((size_t)1024 * 1024 * 2);
  bf16_t* G2T   = (bf16_t*)take((size_t)1024 * 64 * 2);
  bf16_t* xg1b  = (bf16_t*)take((size_t)4096 * 64 * 2);
  bf16_t* qrb   = (bf16_t*)take((size_t)32 * 2048 * 128 * 2);
  bf16_t* krb   = (bf16_t*)take((size_t)32 * 2048 * 128 * 2);
  bf16_t* vbb   = (bf16_t*)take((size_t)32 * 2048 * 64 * 2);
  float*  cst   = (float*)take((size_t)32 * 16 * 8192 * 4);
  bf16_t* pst   = (bf16_t*)take((size_t)32 * 16 * 8192 * 2);
  float*  owo   = (float*)take((size_t)4096 * 1024 * 4);    // reused as lrpe table (disjoint lifetime)
  bf16_t* attno = xb;                 // alias: xb dead after QKV gemm
  float2* lrpe  = (float2*)owo;       // alias: table dead before WO gemm writes owo

  dim3 tb(32, 8);
  f32_to_bf16_kernel<<<2048, 256, 0, stream>>>(x, xb);
  transpose4_kernel<<<dim3(32, 32, 4), tb, 0, stream>>>(
      Wq, Wk, Wv, Wo, qkvT, qkvT + (size_t)1024 * 1024, qkvT + (size_t)2048 * 1024, WoT);
  transpose_f32_bf16_kernel<<<dim3(32, 2), tb, 0, stream>>>(G2, G2T, 64, 1024);
  xg1_kernel<<<512, 512, 0, stream>>>(x, G1, xg1b);
  lrpe_table2_kernel<<<dim3(4, 64), 256, 0, stream>>>(theta, lrpe);

  // fused QKV projection: M=4096, N=3072, K=1024 ; 128x256 tiles -> 384 blocks
  gemm2<EP_QKV, 128, 256, 12, 2, 2><<<384, 256, 0, stream>>>(
      xb, qkvT, lrpe, nullptr, qrb, krb, vbb, nullptr, nullptr, 1024);

  chunk_state_kernel<<<dim3(16, 32), 256, 0, stream>>>(krb, vbb, cst);
  prefix_state_kernel<<<dim3(8, 32), 256, 0, stream>>>(cst, pst);

  attn_kernel<<<dim3(16, 32), 256, 0, stream>>>(qrb, krb, vbb, pst, attno);

  // owo = (attno @ Wo) * sigmoid(xg1b @ G2) : 64x128 tiles -> 512 blocks
  gemm_wo<<<512, 256, 0, stream>>>(attno, WoT, xg1b, G2T, owo, 1024);

  ln_kernel<<<4096, 256, 0, stream>>>(owo, gamma, beta, (float*)d_out);
}

// Round 10
// 133.206 us; speedup vs baseline: 1.6865x; 1.6865x over previous
//
#include <hip/hip_runtime.h>
#include <hip/hip_bf16.h>
#include <cstdint>
#include <cstddef>

typedef __bf16 bf16_t;
typedef __bf16 bf16x4 __attribute__((ext_vector_type(4)));
typedef __bf16 bf16x8 __attribute__((ext_vector_type(8)));
typedef float  f32x4  __attribute__((ext_vector_type(4)));

enum { EP_QKV = 0 };

// async global->LDS, 16B per lane; LDS dest = wave-uniform base + lane*16
__device__ __forceinline__ void async_copy16(const void* g, void* l) {
  __builtin_amdgcn_global_load_lds(
      (const __attribute__((address_space(1))) void*)g,
      (__attribute__((address_space(3))) void*)l, 16, 0, 0);
}

// 4x fused: in [1024][1024] f32 -> out [1024][1024]^T bf16, selected by blockIdx.z
__global__ void transpose4_kernel(const float* __restrict__ w0, const float* __restrict__ w1,
                                  const float* __restrict__ w2, const float* __restrict__ w3,
                                  bf16_t* __restrict__ o0, bf16_t* __restrict__ o1,
                                  bf16_t* __restrict__ o2, bf16_t* __restrict__ o3) {
  int z = blockIdx.z;
  const float* in = (z == 0) ? w0 : (z == 1) ? w1 : (z == 2) ? w2 : w3;
  bf16_t* out = (z == 0) ? o0 : (z == 1) ? o1 : (z == 2) ? o2 : o3;
  __shared__ float tile[32][33];
  int x = threadIdx.x, y = threadIdx.y;
  int c0 = blockIdx.x * 32, r0 = blockIdx.y * 32;
  #pragma unroll
  for (int i = 0; i < 32; i += 8) tile[y + i][x] = in[(size_t)(r0 + y + i) * 1024 + c0 + x];
  __syncthreads();
  #pragma unroll
  for (int i = 0; i < 32; i += 8)
    out[(size_t)(c0 + y + i) * 1024 + r0 + x] = (__bf16)tile[x][y + i];
}

// in [rows][cols] f32 -> out [cols][rows] bf16 ; rows, cols multiples of 32
__global__ void transpose_f32_bf16_kernel(const float* __restrict__ in, bf16_t* __restrict__ out,
                                          int rows, int cols) {
  __shared__ float tile[32][33];
  int x = threadIdx.x, y = threadIdx.y;
  int c0 = blockIdx.x * 32, r0 = blockIdx.y * 32;
  #pragma unroll
  for (int i = 0; i < 32; i += 8) tile[y + i][x] = in[(size_t)(r0 + y + i) * cols + c0 + x];
  __syncthreads();
  #pragma unroll
  for (int i = 0; i < 32; i += 8)
    out[(size_t)(c0 + y + i) * rows + r0 + x] = (__bf16)tile[x][y + i];
}

// ---------------- LRPE cos/sin table via rotation recurrence ----------------

__global__ __launch_bounds__(256) void lrpe_table2_kernel(const float* __restrict__ theta,
                                                          float2* __restrict__ tab) {
  int col = blockIdx.x * 256 + threadIdx.x;
  int n0 = blockIdx.y * 32;
  float th = theta[col];
  float c0, s0, dc, ds;
  sincosf(th * (float)n0, &s0, &c0);
  sincosf(th, &ds, &dc);
  float2* p = tab + (size_t)n0 * 1024 + col;
  #pragma unroll
  for (int i = 0; i < 32; ++i) {
    *p = make_float2(c0, s0);
    float c1 = c0 * dc - s0 * ds;
    float s1 = s0 * dc + c0 * ds;
    c0 = c1; s0 = s1;
    p += 1024;
  }
}

// ---------------- GEMM (R8 best config + hoisted addressing) ----------------
// 128x128 tile, 4 waves, single 32KB buffer, rolled K-loop (runtime K + unroll 1).
// NEW vs R8: (a) __launch_bounds__(256,3) authorizes the VGPR budget matching the
// real occupancy (3 blocks/CU, LDS-capped), (b) global staging pointers hoisted
// out of the K-loop (loop-carried += BK: kills the per-step 64-bit mul-adds),
// (c) swizzled ds_read offsets precomputed (k0-invariant). Attacks VALUBusy=29%.

template <int MODE, int BM, int BN, int GX, int WAVES_M, int WAVES_N>
__global__ __launch_bounds__(WAVES_M * WAVES_N * 64, 3) void gemm2(
    const bf16_t* __restrict__ A, const bf16_t* __restrict__ Bt,
    const float2* __restrict__ lrpe,
    bf16_t* __restrict__ qrb, bf16_t* __restrict__ krb, bf16_t* __restrict__ vbb,
    int K) {
  constexpr int BK = 64;
  constexpr int WAVES = WAVES_M * WAVES_N;
  constexpr int T = WAVES * 64;
  constexpr int WM = BM / WAVES_M, WN = BN / WAVES_N;
  constexpr int MT = WM / 16, NT = WN / 16;
  constexpr int ALD = BM * 8 / T, BLD = BN * 8 / T;
  __shared__ alignas(16) bf16_t lA[BM * BK];
  __shared__ alignas(16) bf16_t lB[BN * BK];
  const int tid = threadIdx.x, w = tid >> 6, l = tid & 63;
  const int wm = w / WAVES_N, wn = w % WAVES_N;
  const int l15 = l & 15, lg = l >> 4;
  const int cpx = gridDim.x >> 3;
  const int id = blockIdx.x;
  const int sw = (id & 7) * cpx + (id >> 3);   // XCD-contiguous, bijective (grid%8==0)
  const int by = sw / GX, bx = sw % GX;
  const int r0 = by * BM, c0 = bx * BN;
  const int srow_l = l >> 3, sslot = l & 7;

  // hoisted global source pointers (advance by BK each K-step)
  const bf16_t* ap[ALD];
  const bf16_t* bp[BLD];
  #pragma unroll
  for (int i = 0; i < ALD; ++i) {
    int seg = i * WAVES + w, row = seg * 8 + srow_l, xs = sslot ^ (row & 7);
    ap[i] = A + (size_t)(r0 + row) * K + xs * 8;
  }
  #pragma unroll
  for (int i = 0; i < BLD; ++i) {
    int seg = i * WAVES + w, row = seg * 8 + srow_l, xs = sslot ^ (row & 7);
    bp[i] = Bt + (size_t)(c0 + row) * K + xs * 8;
  }
  // hoisted swizzled LDS read offsets (elements), k0-invariant
  int aoffs[MT][2], boffs[NT][2];
  #pragma unroll
  for (int mt = 0; mt < MT; ++mt) {
    int row = wm * WM + mt * 16 + l15, rb = row * BK, r7 = row & 7;
    aoffs[mt][0] = rb + (lg ^ r7) * 8;
    aoffs[mt][1] = rb + ((4 + lg) ^ r7) * 8;
  }
  #pragma unroll
  for (int nt = 0; nt < NT; ++nt) {
    int row = wn * WN + nt * 16 + l15, rb = row * BK, r7 = row & 7;
    boffs[nt][0] = rb + (lg ^ r7) * 8;
    boffs[nt][1] = rb + ((4 + lg) ^ r7) * 8;
  }

  f32x4 acc[MT][NT] = {};
  const int nsteps = K / BK;
  #pragma unroll 1
  for (int t = 0; t < nsteps; ++t) {
    #pragma unroll
    for (int i = 0; i < ALD; ++i) {
      async_copy16(ap[i], lA + (i * WAVES + w) * 512);
      ap[i] += BK;
    }
    #pragma unroll
    for (int i = 0; i < BLD; ++i) {
      async_copy16(bp[i], lB + (i * WAVES + w) * 512);
      bp[i] += BK;
    }
    __syncthreads();
    #pragma unroll
    for (int ks = 0; ks < 2; ++ks) {
      bf16x8 af[MT], bfr[NT];
      #pragma unroll
      for (int mt = 0; mt < MT; ++mt) af[mt] = *(const bf16x8*)(lA + aoffs[mt][ks]);
      #pragma unroll
      for (int nt = 0; nt < NT; ++nt) bfr[nt] = *(const bf16x8*)(lB + boffs[nt][ks]);
      #pragma unroll
      for (int mt = 0; mt < MT; ++mt)
        #pragma unroll
        for (int nt = 0; nt < NT; ++nt)
          acc[mt][nt] = __builtin_amdgcn_mfma_f32_16x16x32_bf16(af[mt], bfr[nt], acc[mt][nt], 0, 0, 0);
    }
    __syncthreads();
  }
  #pragma unroll
  for (int mt = 0; mt < MT; ++mt)
  #pragma unroll
  for (int nt = 0; nt < NT; ++nt)
  #pragma unroll
  for (int r = 0; r < 4; ++r) {
    int grow = r0 + wm * WM + mt * 16 + lg * 4 + r;
    int gcol = c0 + wn * WN + nt * 16 + l15;
    float v = acc[mt][nt][r];
    if constexpr (MODE == EP_QKV) {
      int sect = gcol >> 10, col = gcol & 1023;   // block-uniform sect
      int b = grow >> 11, n = grow & 2047;
      int h = col >> 6, d = col & 63;
      if (sect == 2) {
        vbb[((size_t)(b * 16 + h) * 2048 + n) * 64 + d] = (__bf16)v;
      } else {
        float sv = v / (1.f + expf(-v));      // silu
        float2 cs = lrpe[(size_t)n * 1024 + col];
        bf16_t* dst = sect ? krb : qrb;
        size_t base = ((size_t)(b * 16 + h) * 2048 + n) * 128 + d;
        dst[base] = (__bf16)(sv * cs.x);
        dst[base + 64] = (__bf16)(sv * cs.y);
      }
    }
  }
}

// ---------------- WO GEMM with fused gate: owo = (attno @ Wo) * sigmoid(xg1b @ G2) ----------------
// 64x128 tile; RUNTIME K + unroll 1 keeps the loop rolled. (R8-identical.)

__global__ __launch_bounds__(256) void gemm_wo(
    const bf16_t* __restrict__ A, const bf16_t* __restrict__ Bt,
    const bf16_t* __restrict__ xg1b, const bf16_t* __restrict__ G2T,
    float* __restrict__ fout, int K) {
  constexpr int BK = 64, GX = 8;
  __shared__ alignas(16) bf16_t lA[64 * BK];
  __shared__ alignas(16) bf16_t lB[128 * BK];
  const int tid = threadIdx.x, w = tid >> 6, l = tid & 63;
  const int wm = w >> 1, wn = w & 1;
  const int l15 = l & 15, lg = l >> 4;
  const int cpx = gridDim.x >> 3;
  const int id = blockIdx.x;
  const int sw = (id & 7) * cpx + (id >> 3);
  const int by = sw / GX, bx = sw % GX;
  const int r0 = by * 64, c0 = bx * 128;
  const int srow_l = l >> 3, sslot = l & 7;
  f32x4 acc[2][4] = {};
  #pragma unroll 1
  for (int k0 = 0; k0 < K; k0 += BK) {
    #pragma unroll
    for (int i = 0; i < 2; ++i) {
      int seg = i * 4 + w, row = seg * 8 + srow_l, xs = sslot ^ (row & 7);
      async_copy16(A + (size_t)(r0 + row) * K + k0 + xs * 8, lA + seg * 512);
    }
    #pragma unroll
    for (int i = 0; i < 4; ++i) {
      int seg = i * 4 + w, row = seg * 8 + srow_l, xs = sslot ^ (row & 7);
      async_copy16(Bt + (size_t)(c0 + row) * K + k0 + xs * 8, lB + seg * 512);
    }
    __syncthreads();
    #pragma unroll
    for (int ks = 0; ks < 2; ++ks) {
      bf16x8 af[2], bfr[4];
      #pragma unroll
      for (int mt = 0; mt < 2; ++mt) {
        int row = wm * 32 + mt * 16 + l15;
        int s = (ks * 4 + lg) ^ (row & 7);
        af[mt] = *(const bf16x8*)(lA + row * BK + s * 8);
      }
      #pragma unroll
      for (int nt = 0; nt < 4; ++nt) {
        int row = wn * 64 + nt * 16 + l15;
        int s = (ks * 4 + lg) ^ (row & 7);
        bfr[nt] = *(const bf16x8*)(lB + row * BK + s * 8);
      }
      #pragma unroll
      for (int mt = 0; mt < 2; ++mt)
        #pragma unroll
        for (int nt = 0; nt < 4; ++nt)
          acc[mt][nt] = __builtin_amdgcn_mfma_f32_16x16x32_bf16(af[mt], bfr[nt], acc[mt][nt], 0, 0, 0);
    }
    __syncthreads();
  }
  // ---- fused gate K-step ----
  #pragma unroll
  for (int i = 0; i < 2; ++i) {
    int seg = i * 4 + w, row = seg * 8 + srow_l, xs = sslot ^ (row & 7);
    async_copy16(xg1b + (size_t)(r0 + row) * 64 + xs * 8, lA + seg * 512);
  }
  #pragma unroll
  for (int i = 0; i < 4; ++i) {
    int seg = i * 4 + w, row = seg * 8 + srow_l, xs = sslot ^ (row & 7);
    async_copy16(G2T + (size_t)(c0 + row) * 64 + xs * 8, lB + seg * 512);
  }
  __syncthreads();
  f32x4 acc2[2][4] = {};
  #pragma unroll
  for (int ks = 0; ks < 2; ++ks) {
    bf16x8 af[2], bfr[4];
    #pragma unroll
    for (int mt = 0; mt < 2; ++mt) {
      int row = wm * 32 + mt * 16 + l15;
      int s = (ks * 4 + lg) ^ (row & 7);
      af[mt] = *(const bf16x8*)(lA + row * BK + s * 8);
    }
    #pragma unroll
    for (int nt = 0; nt < 4; ++nt) {
      int row = wn * 64 + nt * 16 + l15;
      int s = (ks * 4 + lg) ^ (row & 7);
      bfr[nt] = *(const bf16x8*)(lB + row * BK + s * 8);
    }
    #pragma unroll
    for (int mt = 0; mt < 2; ++mt)
      #pragma unroll
      for (int nt = 0; nt < 4; ++nt)
        acc2[mt][nt] = __builtin_amdgcn_mfma_f32_16x16x32_bf16(af[mt], bfr[nt], acc2[mt][nt], 0, 0, 0);
  }
  #pragma unroll
  for (int mt = 0; mt < 2; ++mt)
  #pragma unroll
  for (int nt = 0; nt < 4; ++nt)
  #pragma unroll
  for (int r = 0; r < 4; ++r) {
    int grow = r0 + wm * 32 + mt * 16 + lg * 4 + r;
    int gcol = c0 + wn * 64 + nt * 16 + l15;
    float g = 1.f / (1.f + expf(-acc2[mt][nt][r]));
    fout[(size_t)grow * 1024 + gcol] = acc[mt][nt][r] * g;
  }
}

// ---------------- xg1b = bf16(x @ G1), AND xb = bf16(x) (x read once) ----------------

__global__ __launch_bounds__(512) void xg1_kernel(const float* __restrict__ x,
                                                  const float* __restrict__ G1,
                                                  bf16_t* __restrict__ xg1b,
                                                  bf16_t* __restrict__ xb) {
  int r0 = blockIdx.x * 8, t = threadIdx.x;
  __shared__ float xs[8][1024];
  __shared__ float part[8][8][64];
  const float* xr = x + (size_t)r0 * 1024;
  bf16_t* xbr = xb + (size_t)r0 * 1024;
  #pragma unroll
  for (int i = 0; i < 4; ++i) {
    float4 v = ((const float4*)xr)[t + i * 512];
    ((float4*)&xs[0][0])[t + i * 512] = v;
    bf16x4 o;
    o[0] = (__bf16)v.x; o[1] = (__bf16)v.y; o[2] = (__bf16)v.z; o[3] = (__bf16)v.w;
    *(bf16x4*)(xbr + (size_t)(t + i * 512) * 4) = o;
  }
  __syncthreads();
  int cc = t & 63, kh = t >> 6;
  float acc[8] = {0, 0, 0, 0, 0, 0, 0, 0};
  for (int k = kh * 128; k < kh * 128 + 128; ++k) {
    float g = G1[(size_t)k * 64 + cc];
    #pragma unroll
    for (int rr = 0; rr < 8; ++rr) acc[rr] += xs[rr][k] * g;
  }
  #pragma unroll
  for (int rr = 0; rr < 8; ++rr) part[kh][rr][cc] = acc[rr];
  __syncthreads();
  int r2 = t >> 6, c2 = t & 63;
  float s2 = 0.f;
  #pragma unroll
  for (int j = 0; j < 8; ++j) s2 += part[j][r2][c2];
  xg1b[(size_t)(r0 + r2) * 64 + c2] = (__bf16)s2;
}

// ---------------- chunk states: cstate[bh][c][dv][dk] = sum_m v[m][dv]*k[m][dk] ----------------

__global__ __launch_bounds__(256) void chunk_state_kernel(const bf16_t* __restrict__ kr,
                                                          const bf16_t* __restrict__ vb,
                                                          float* __restrict__ cstate) {
  const int c = blockIdx.x, bh = blockIdx.y;
  const int tid = threadIdx.x, w = tid >> 6, l = tid & 63;
  const int l15 = l & 15, lg = l >> 4;
  __shared__ alignas(16) bf16_t kT[128][144];
  __shared__ alignas(16) bf16_t vT[64][144];
  const bf16_t* kb = kr + ((size_t)bh * 2048 + c * 128) * 128;
  const bf16_t* vsrc = vb + ((size_t)bh * 2048 + c * 128) * 64;
  {
    int m = tid >> 1, half = tid & 1;
    #pragma unroll
    for (int i = 0; i < 8; ++i) {
      bf16x8 kv = *(const bf16x8*)(kb + (size_t)m * 128 + half * 64 + i * 8);
      #pragma unroll
      for (int j = 0; j < 8; ++j) kT[half * 64 + i * 8 + j][m] = kv[j];
    }
    int dv0 = half * 32;
    #pragma unroll
    for (int i = 0; i < 4; ++i) {
      bf16x8 vv = *(const bf16x8*)(vsrc + (size_t)m * 64 + dv0 + i * 8);
      #pragma unroll
      for (int j = 0; j < 8; ++j) vT[dv0 + i * 8 + j][m] = vv[j];
    }
  }
  __syncthreads();
  f32x4 acc[4][2] = {};
  #pragma unroll
  for (int km = 0; km < 4; ++km) {
    bf16x8 a[4], b2[2];
    #pragma unroll
    for (int mt = 0; mt < 4; ++mt) a[mt] = *(const bf16x8*)&vT[mt * 16 + l15][km * 32 + lg * 8];
    #pragma unroll
    for (int nt = 0; nt < 2; ++nt) b2[nt] = *(const bf16x8*)&kT[w * 32 + nt * 16 + l15][km * 32 + lg * 8];
    #pragma unroll
    for (int mt = 0; mt < 4; ++mt)
      #pragma unroll
      for (int nt = 0; nt < 2; ++nt)
        acc[mt][nt] = __builtin_amdgcn_mfma_f32_16x16x32_bf16(a[mt], b2[nt], acc[mt][nt], 0, 0, 0);
  }
  float* out = cstate + ((size_t)bh * 16 + c) * 8192;
  #pragma unroll
  for (int mt = 0; mt < 4; ++mt)
  #pragma unroll
  for (int nt = 0; nt < 2; ++nt)
  #pragma unroll
  for (int r = 0; r < 4; ++r) {
    int dv = mt * 16 + lg * 4 + r;
    int dk = w * 32 + nt * 16 + l15;
    out[dv * 128 + dk] = acc[mt][nt][r];
  }
}

// ---------------- exclusive prefix over chunks (256 blocks: 8 e-slices x 32 bh) ----------------

__global__ __launch_bounds__(256) void prefix_state_kernel(const float* __restrict__ cstate,
                                                           bf16_t* __restrict__ pstate) {
  int bh = blockIdx.y;
  int e0 = blockIdx.x * 1024 + threadIdx.x * 4;
  const float* cs = cstate + (size_t)bh * 16 * 8192 + e0;
  bf16_t* ps = pstate + (size_t)bh * 16 * 8192 + e0;
  float ax = 0.f, ay = 0.f, az = 0.f, aw = 0.f;
  #pragma unroll
  for (int c = 0; c < 16; ++c) {
    bf16x4 o;
    o[0] = (__bf16)ax; o[1] = (__bf16)ay; o[2] = (__bf16)az; o[3] = (__bf16)aw;
    *(bf16x4*)(ps + (size_t)c * 8192) = o;
    float4 v = *(const float4*)(cs + (size_t)c * 8192);
    ax += v.x; ay += v.y; az += v.z; aw += v.w;
  }
}

// ---------------- attention per (b,h,chunk): out = q@S + (q@k^T ∘ tril)@v ----------------

__global__ __launch_bounds__(256) void attn_kernel(const bf16_t* __restrict__ qr,
                                                   const bf16_t* __restrict__ kr,
                                                   const bf16_t* __restrict__ vb,
                                                   const bf16_t* __restrict__ pstate,
                                                   bf16_t* __restrict__ attno) {
  const int c = blockIdx.x, bh = blockIdx.y;
  const int b = bh >> 4, h = bh & 15;
  const int tid = threadIdx.x, w = tid >> 6, l = tid & 63;
  const int wr = w >> 1, wc = w & 1, l15 = l & 15, lg = l >> 4;
  __shared__ alignas(16) bf16_t e_lds[128][144];
  __shared__ alignas(16) bf16_t vT[64][144];
  const int n0 = c * 128;
  const bf16_t* qb = qr + (size_t)bh * 2048 * 128;
  const bf16_t* kb = kr + (size_t)bh * 2048 * 128;
  const bf16_t* vsrc = vb + ((size_t)bh * 2048 + n0) * 64;
  const bf16_t* sb = pstate + ((size_t)bh * 16 + c) * 8192;
  {  // stage v^T
    int m = tid >> 1, dv0 = (tid & 1) * 32;
    #pragma unroll
    for (int i = 0; i < 4; ++i) {
      bf16x8 vv = *(const bf16x8*)(vsrc + (size_t)m * 64 + dv0 + i * 8);
      #pragma unroll
      for (int j = 0; j < 8; ++j) vT[dv0 + i * 8 + j][m] = vv[j];
    }
  }
  f32x4 acc_e[4][4] = {};
  f32x4 acc[4][2] = {};
  #pragma unroll
  for (int kk = 0; kk < 4; ++kk) {  // K over dk=128
    bf16x8 af[4], bk[4], bs[2];
    #pragma unroll
    for (int mt = 0; mt < 4; ++mt)
      af[mt] = *(const bf16x8*)(qb + (size_t)(n0 + wr * 64 + mt * 16 + l15) * 128 + kk * 32 + lg * 8);
    #pragma unroll
    for (int nt = 0; nt < 4; ++nt)
      bk[nt] = *(const bf16x8*)(kb + (size_t)(n0 + wc * 64 + nt * 16 + l15) * 128 + kk * 32 + lg * 8);
    #pragma unroll
    for (int nt = 0; nt < 2; ++nt)
      bs[nt] = *(const bf16x8*)(sb + (size_t)(wc * 32 + nt * 16 + l15) * 128 + kk * 32 + lg * 8);
    #pragma unroll
    for (int mt = 0; mt < 4; ++mt) {
      #pragma unroll
      for (int nt = 0; nt < 4; ++nt)
        acc_e[mt][nt] = __builtin_amdgcn_mfma_f32_16x16x32_bf16(af[mt], bk[nt], acc_e[mt][nt], 0, 0, 0);
      #pragma unroll
      for (int nt = 0; nt < 2; ++nt)
        acc[mt][nt] = __builtin_amdgcn_mfma_f32_16x16x32_bf16(af[mt], bs[nt], acc[mt][nt], 0, 0, 0);
    }
  }
  #pragma unroll
  for (int mt = 0; mt < 4; ++mt)
  #pragma unroll
  for (int nt = 0; nt < 4; ++nt)
  #pragma unroll
  for (int r = 0; r < 4; ++r) {
    int row = wr * 64 + mt * 16 + lg * 4 + r;   // n (query)
    int col = wc * 64 + nt * 16 + l15;          // m (key)
    float v = (col <= row) ? acc_e[mt][nt][r] : 0.f;
    e_lds[row][col] = (__bf16)v;
  }
  __syncthreads();
  #pragma unroll
  for (int km = 0; km < 4; ++km) {  // K over m=128
    bf16x8 af[4], bv[2];
    #pragma unroll
    for (int mt = 0; mt < 4; ++mt)
      af[mt] = *(const bf16x8*)&e_lds[wr * 64 + mt * 16 + l15][km * 32 + lg * 8];
    #pragma unroll
    for (int nt = 0; nt < 2; ++nt)
      bv[nt] = *(const bf16x8*)&vT[wc * 32 + nt * 16 + l15][km * 32 + lg * 8];
    #pragma unroll
    for (int mt = 0; mt < 4; ++mt)
      #pragma unroll
      for (int nt = 0; nt < 2; ++nt)
        acc[mt][nt] = __builtin_amdgcn_mfma_f32_16x16x32_bf16(af[mt], bv[nt], acc[mt][nt], 0, 0, 0);
  }
  #pragma unroll
  for (int mt = 0; mt < 4; ++mt)
  #pragma unroll
  for (int nt = 0; nt < 2; ++nt)
  #pragma unroll
  for (int r = 0; r < 4; ++r) {
    int row = n0 + wr * 64 + mt * 16 + lg * 4 + r;
    int dv = wc * 32 + nt * 16 + l15;
    attno[((size_t)b * 2048 + row) * 1024 + h * 64 + dv] = (__bf16)acc[mt][nt][r];
  }
}

// ---------------- LayerNorm ----------------

__global__ __launch_bounds__(256) void ln_kernel(const float* __restrict__ owo,
                                                 const float* __restrict__ gamma,
                                                 const float* __restrict__ beta,
                                                 float* __restrict__ out) {
  int r = blockIdx.x, t = threadIdx.x;
  const float4 o = ((const float4*)(owo + (size_t)r * 1024))[t];
  float sum = o.x + o.y + o.z + o.w;
  float ss = o.x * o.x + o.y * o.y + o.z * o.z + o.w * o.w;
  #pragma unroll
  for (int off = 32; off > 0; off >>= 1) {
    sum += __shfl_down(sum, off);
    ss += __shfl_down(ss, off);
  }
  __shared__ float rs[4], rq[4];
  if ((t & 63) == 0) { rs[t >> 6] = sum; rq[t >> 6] = ss; }
  __syncthreads();
  sum = rs[0] + rs[1] + rs[2] + rs[3];
  ss = rq[0] + rq[1] + rq[2] + rq[3];
  float mean = sum * (1.f / 1024.f);
  float var = ss * (1.f / 1024.f) - mean * mean;
  float inv = rsqrtf(var + 1e-5f);
  const float4 g = ((const float4*)gamma)[t];
  const float4 be = ((const float4*)beta)[t];
  float4 res;
  res.x = (o.x - mean) * inv * g.x + be.x;
  res.y = (o.y - mean) * inv * g.y + be.y;
  res.z = (o.z - mean) * inv * g.z + be.z;
  res.w = (o.w - mean) * inv * g.w + be.w;
  ((float4*)(out + (size_t)r * 1024))[t] = res;
}

// ---------------- launch ----------------

extern "C" void kernel_launch(void* const* d_in, const int* in_sizes, int n_in,
                              void* d_out, int out_size, void* d_ws, size_t ws_size,
                              hipStream_t stream) {
  const float* x = (const float*)d_in[0];
  const float* Wq = (const float*)d_in[1];
  const float* Wk = (const float*)d_in[2];
  const float* Wv = (const float*)d_in[3];
  const float* Wo = (const float*)d_in[4];
  const float* G1 = (const float*)d_in[5];
  const float* G2 = (const float*)d_in[6];
  const float* gamma = (const float*)d_in[7];
  const float* beta = (const float*)d_in[8];
  const float* theta = (const float*)d_in[9];

  char* w8 = (char*)d_ws;
  size_t off = 0;
  auto take = [&](size_t n) { char* p = w8 + off; off += (n + 255) & ~(size_t)255; return (void*)p; };

  bf16_t* xb    = (bf16_t*)take((size_t)4096 * 1024 * 2);   // reused as attno
  bf16_t* qkvT  = (bf16_t*)take((size_t)3072 * 1024 * 2);   // [WqT|WkT|WvT]
  bf16_t* WoT   = (bf16_t*)take((size_t)1024 * 1024 * 2);
  bf16_t* G2T   = (bf16_t*)take((size_t)1024 * 64 * 2);
  bf16_t* xg1b  = (bf16_t*)take((size_t)4096 * 64 * 2);
  bf16_t* qrb   = (bf16_t*)take((size_t)32 * 2048 * 128 * 2);
  bf16_t* krb   = (bf16_t*)take((size_t)32 * 2048 * 128 * 2);
  bf16_t* vbb   = (bf16_t*)take((size_t)32 * 2048 * 64 * 2);
  float*  cst   = (float*)take((size_t)32 * 16 * 8192 * 4);
  bf16_t* pst   = (bf16_t*)take((size_t)32 * 16 * 8192 * 2);
  float*  owo   = (float*)take((size_t)4096 * 1024 * 4);    // reused as lrpe table (disjoint lifetime)
  bf16_t* attno = xb;                 // alias: xb dead after QKV gemm
  float2* lrpe  = (float2*)owo;       // alias: table dead before WO gemm writes owo

  dim3 tb(32, 8);
  xg1_kernel<<<512, 512, 0, stream>>>(x, G1, xg1b, xb);   // also emits xb (x read once)
  transpose4_kernel<<<dim3(32, 32, 4), tb, 0, stream>>>(
      Wq, Wk, Wv, Wo, qkvT, qkvT + (size_t)1024 * 1024, qkvT + (size_t)2048 * 1024, WoT);
  transpose_f32_bf16_kernel<<<dim3(32, 2), tb, 0, stream>>>(G2, G2T, 64, 1024);
  lrpe_table2_kernel<<<dim3(4, 64), 256, 0, stream>>>(theta, lrpe);

  // fused QKV projection: M=4096, N=3072, K=1024 ; 128x128 tiles -> 768 blocks
  gemm2<EP_QKV, 128, 128, 24, 2, 2><<<768, 256, 0, stream>>>(
      xb, qkvT, lrpe, qrb, krb, vbb, 1024);

  chunk_state_kernel<<<dim3(16, 32), 256, 0, stream>>>(krb, vbb, cst);
  prefix_state_kernel<<<dim3(8, 32), 256, 0, stream>>>(cst, pst);

  attn_kernel<<<dim3(16, 32), 256, 0, stream>>>(qrb, krb, vbb, pst, attno);

  // owo = (attno @ Wo) * sigmoid(xg1b @ G2) : 64x128 tiles -> 512 blocks
  gemm_wo<<<512, 256, 0, stream>>>(attno, WoT, xg1b, G2T, owo, 1024);

  ln_kernel<<<4096, 256, 0, stream>>>(owo, gamma, beta, (float*)d_out);
}